// Round 6
// baseline (687.171 us; speedup 1.0000x reference)
//
#include <hip/hip_runtime.h>

// Conv2D with per-batch gumbel-sigmoid weight dropout, MI355X (gfx950). v3.
// Changes vs v2 (197us, MfmaUtil 25.6%, Occ 42%, LDS-supply/latency-bound):
//  - 2-term split: A bf16-hi only (AhBh + AhBl); B stays hi/lo. Drops the
//    entire sAlo plane: LDS bytes, staging VALU, and 1/3 of MFMAs. Added
//    error ~1.3e-3 << mask-boundary-driven absmax 0.0156.
//  - tile 16x32 (halo 34x18), LDS 39.2KB -> 4 blocks/CU (2048 thr, CU-full).
//    __launch_bounds__(512,8) caps VGPR at 64 for 8 waves/SIMD.
//  - g-plane stride padded +2 u16 (2449 words === 1 mod 4): the 4 16-lane
//    groups of a ds_read_b128 cover all 4 bank-residue classes per phase
//    -> 2-way (free) instead of 8-way aliasing.

typedef unsigned short u16;
typedef unsigned int   u32;
typedef __attribute__((ext_vector_type(4))) unsigned short u16x4;
typedef __attribute__((ext_vector_type(8))) __bf16 bf16x8;
typedef __attribute__((ext_vector_type(4))) float  f32x4;

#define EPSF 1e-30f

__device__ __forceinline__ u16 f2bf(float f) {
    u32 x = __float_as_uint(f);
    x += 0x7fffu + ((x >> 16) & 1u);
    return (u16)(x >> 16);
}
__device__ __forceinline__ float bf2f(u16 h) {
    return __uint_as_float(((u32)h) << 16);
}

// ---------------------------------------------------------------------------
// prep: masked kernel (bf16 hi/lo, B-frag layout) + masked bias (unchanged)
// dst index: (((b*9+t)*4 + ci/8)*32 + f)*8 + ci%8   (1024 u16 per (b,t))
// ws: kw_hi[73728 u16] | kw_lo[73728 u16] | mbias[256 f32]
// ---------------------------------------------------------------------------
__global__ __launch_bounds__(256) void prep_kernel(
    const float* __restrict__ kern, const float* __restrict__ bias,
    const float* __restrict__ unif_c, const float* __restrict__ unif_b,
    u16* __restrict__ kw_hi, u16* __restrict__ kw_lo,
    float* __restrict__ mbias)
{
    int flat = blockIdx.x * 256 + threadIdx.x;
    if (flat < 73728) {
        int f  = flat & 31;
        int ci = (flat >> 5) & 31;
        int t  = (flat >> 10) % 9;
        int b  = flat / 9216;
        float k = kern[flat % 9216];
        float u = unif_c[flat];
        float lp = logf(0.25f);
        float p  = 1.0f / (1.0f + expf(-lp));
        float logit = logf(p + EPSF) - logf(1.0f - p + EPSF)
                    + logf(u + EPSF) - logf(1.0f - u + EPSF);
        float s  = 1.0f / (1.0f + expf(-(logit / 0.01f)));
        float w  = k * (1.0f - s);
        u16 hi = f2bf(w);
        u16 lo = f2bf(w - bf2f(hi));
        int g = ci >> 3, j = ci & 7;
        int dst = (((b * 9 + t) * 4 + g) * 32 + f) * 8 + j;
        kw_hi[dst] = hi;
        kw_lo[dst] = lo;
    } else if (flat < 73728 + 256) {
        int idx = flat - 73728;
        int f = idx & 31;
        float u = unif_b[idx];
        float logit = logf(0.2f + EPSF) - logf(0.8f + EPSF)
                    + logf(u + EPSF) - logf(1.0f - u + EPSF);
        float s = 1.0f / (1.0f + expf(-(logit / 0.01f)));
        mbias[idx] = bias[f] * (1.0f - s);
    }
}

// ---------------------------------------------------------------------------
// conv v3: grid (32, 16, 8), block 512 (8 waves).
// Block tile: 16 x-px x 32 y-rows x 32 F. Wave w: rows w*4 .. w*4+3.
// LDS: input halo 34x18x32 bf16 (hi only), [g][row34][col18][8ch],
//      g-plane stride 34*18*8+2 u16 (bank-residue pad).
// ---------------------------------------------------------------------------
#define TROWS 32
#define HROWS 34
#define PLSTRIDE (HROWS * 18 * 8 + 2)   // 4898 u16; 2449 words === 1 (mod 4)

__global__ __launch_bounds__(512, 8) void conv_kernel(
    const float* __restrict__ in,
    const u16* __restrict__ kw_hi, const u16* __restrict__ kw_lo,
    const float* __restrict__ mbias,
    float* __restrict__ out)
{
    __shared__ __align__(16) u16 sA[4 * PLSTRIDE];  // 39184 B

    const int b    = blockIdx.z;
    const int ty0  = blockIdx.y * TROWS;
    const int tx0  = blockIdx.x * 16;
    const int tid  = threadIdx.x;
    const int lane = tid & 63;
    const int wave = tid >> 6;
    const int wrow = wave * 4;   // wave's 4 output rows (tile-local)
    const int lm   = lane & 15;  // A row (x) / B col (f within half)
    const int g    = lane >> 4;  // k-chunk (channels g*8..g*8+7)

    // --- stage input halo 34x18x32 fp32 -> bf16 (hi) LDS ---
    for (int i = tid; i < HROWS * 18 * 8; i += 512) {
        int p   = i >> 3;           // pixel 0 .. 34*18-1
        int row = p / 18;
        int col = p - row * 18;
        int c4  = (i & 7) * 4;      // channel start of this float4
        int gy  = ty0 - 1 + row;
        int gx  = tx0 - 1 + col;
        float4 v = make_float4(0.f, 0.f, 0.f, 0.f);
        if ((unsigned)gy < 512u && (unsigned)gx < 512u) {
            v = *reinterpret_cast<const float4*>(
                in + (((size_t)b * 512 + gy) * 512 + gx) * 32 + c4);
        }
        u16x4 h;
        h.x = f2bf(v.x);
        h.y = f2bf(v.y);
        h.z = f2bf(v.z);
        h.w = f2bf(v.w);
        int gg = c4 >> 3, j0 = c4 & 7;
        int dst = gg * PLSTRIDE + ((row * 18 + col) * 8 + j0);
        *reinterpret_cast<u16x4*>(&sA[dst]) = h;
    }
    __syncthreads();

    // --- main loop: 9 taps; per tap stream 4 B-frags from L2, 4 rows x 4 MFMA
    f32x4 acc[4][2];
    #pragma unroll
    for (int r = 0; r < 4; ++r) {
        acc[r][0] = (f32x4){0.f, 0.f, 0.f, 0.f};
        acc[r][1] = (f32x4){0.f, 0.f, 0.f, 0.f};
    }

    const u16* ph = kw_hi + b * 9216;
    const u16* pl = kw_lo + b * 9216;
    const int foff0 = (g * 32 + lm) * 8;   // f = lm      (half 0)
    const int foff1 = foff0 + 128;         // f = lm + 16 (half 1)

    #pragma unroll
    for (int t = 0; t < 9; ++t) {
        const bf16x8 tbh0 = *reinterpret_cast<const bf16x8*>(ph + t * 1024 + foff0);
        const bf16x8 tbh1 = *reinterpret_cast<const bf16x8*>(ph + t * 1024 + foff1);
        const bf16x8 tbl0 = *reinterpret_cast<const bf16x8*>(pl + t * 1024 + foff0);
        const bf16x8 tbl1 = *reinterpret_cast<const bf16x8*>(pl + t * 1024 + foff1);
        const int ky = t / 3;
        const int kx = t - ky * 3;
        #pragma unroll
        for (int r = 0; r < 4; ++r) {
            const int row = wrow + r + ky;
            const int col = lm + kx;
            const int off = g * PLSTRIDE + ((row * 18 + col) * 8);
            bf16x8 ah = *reinterpret_cast<const bf16x8*>(&sA[off]);
            // 2-term split: Ah*Bh + Ah*Bl (A bf16-quantized, B ~fp32)
            acc[r][0] = __builtin_amdgcn_mfma_f32_16x16x32_bf16(ah, tbh0, acc[r][0], 0, 0, 0);
            acc[r][1] = __builtin_amdgcn_mfma_f32_16x16x32_bf16(ah, tbh1, acc[r][1], 0, 0, 0);
            acc[r][0] = __builtin_amdgcn_mfma_f32_16x16x32_bf16(ah, tbl0, acc[r][0], 0, 0, 0);
            acc[r][1] = __builtin_amdgcn_mfma_f32_16x16x32_bf16(ah, tbl1, acc[r][1], 0, 0, 0);
        }
    }

    // --- epilogue: bias add + store (D: col=lane&15=f, row=(lane>>4)*4+q=x) ---
    const float bsv0 = mbias[b * 32 + lm];
    const float bsv1 = mbias[b * 32 + lm + 16];
    #pragma unroll
    for (int r = 0; r < 4; ++r) {
        const int y = ty0 + wrow + r;
        #pragma unroll
        for (int q = 0; q < 4; ++q) {
            const int x = tx0 + g * 4 + q;
            const size_t base = (((size_t)b * 512 + y) * 512 + x) * 32;
            out[base + lm]      = acc[r][0][q] + bsv0;
            out[base + lm + 16] = acc[r][1][q] + bsv1;
        }
    }
}

// ---------------------------------------------------------------------------
extern "C" void kernel_launch(void* const* d_in, const int* in_sizes, int n_in,
                              void* d_out, int out_size, void* d_ws, size_t ws_size,
                              hipStream_t stream) {
    const float* inputs = (const float*)d_in[0];
    const float* kern   = (const float*)d_in[1];
    const float* bias   = (const float*)d_in[2];
    const float* unif_c = (const float*)d_in[3];
    const float* unif_b = (const float*)d_in[4];
    float* out = (float*)d_out;

    u16*   kw_hi = (u16*)d_ws;
    u16*   kw_lo = kw_hi + 73728;
    float* mbias = (float*)(kw_lo + 73728);

    hipLaunchKernelGGL(prep_kernel, dim3(289), dim3(256), 0, stream,
                       kern, bias, unif_c, unif_b, kw_hi, kw_lo, mbias);
    hipLaunchKernelGGL(conv_kernel, dim3(32, 16, 8), dim3(512), 0, stream,
                       inputs, kw_hi, kw_lo, mbias, out);
}